// Round 13
// baseline (338.860 us; speedup 1.0000x reference)
//
#include <hip/hip_runtime.h>

typedef _Float16 half8 __attribute__((ext_vector_type(8)));
typedef _Float16 half4v __attribute__((ext_vector_type(4)));
typedef float f32x4 __attribute__((ext_vector_type(4)));

#define NB 4
#define SQ 512
#define CL 3584
#define TT 4096
#define DM 2048
#define NH 16
#define DH 128

// XOR swizzles on half-index (attn LDS)
#define KSW(row, col) ((((row) * 128) + (col)) ^ ((((row) & 7) << 3)))
#define VSW(row, col) ((((row) * 64) + (col)) ^ ((((row) & 7) << 3)))
#define PSW(row, col) ((((row) * 64) + (col)) ^ ((((row) & 7) << 3)))
// v9: Ps rows of 32 halves; V paired-line (2 d-rows per 128B line, 8-slot XOR)
#define PSW2(row, col) ((((row) << 5)) + ((col) ^ (((row) & 3) << 3)))
#define VAD(D, g) ((((D) >> 1) * 64) + ((((((D) & 1) << 2) | (g)) ^ (((D) >> 1) & 7)) << 3))

__device__ __forceinline__ void gl_lds16(const void* g, void* l) {
  __builtin_amdgcn_global_load_lds(
      (const __attribute__((address_space(1))) unsigned int*)g,
      (__attribute__((address_space(3))) unsigned int*)l, 16, 0, 0);
}

// ---------------- fp32 -> f16 dense convert, 6 slices in one launch ----------------
__global__ __launch_bounds__(256) void cvt_f16(
    const float* __restrict__ s0, const float* __restrict__ s1, const float* __restrict__ s2,
    const float* __restrict__ s3, const float* __restrict__ s4, const float* __restrict__ s5,
    _Float16* __restrict__ d0, _Float16* __restrict__ d1, _Float16* __restrict__ d2,
    _Float16* __restrict__ d3, _Float16* __restrict__ d4, _Float16* __restrict__ d5)
{
  const int z = blockIdx.y;
  const float* s = z == 0 ? s0 : z == 1 ? s1 : z == 2 ? s2 : z == 3 ? s3 : z == 4 ? s4 : s5;
  _Float16* d = z == 0 ? d0 : z == 1 ? d1 : z == 2 ? d2 : z == 3 ? d3 : z == 4 ? d4 : d5;
  const int n4 = DM * DM / 4;
  for (int v = blockIdx.x * blockDim.x + threadIdx.x; v < n4;
       v += gridDim.x * blockDim.x) {
    float4 x = ((const float4*)s)[v];
    half4v h = { (_Float16)x.x, (_Float16)x.y, (_Float16)x.z, (_Float16)x.w };
    ((half4v*)d)[v] = h;
  }
}

__global__ __launch_bounds__(256) void cvt_f16_one(
    const float* __restrict__ s, _Float16* __restrict__ d)
{
  const int n4 = DM * DM / 4;
  for (int v = blockIdx.x * blockDim.x + threadIdx.x; v < n4;
       v += gridDim.x * blockDim.x) {
    float4 x = ((const float4*)s)[v];
    half4v h = { (_Float16)x.x, (_Float16)x.y, (_Float16)x.z, (_Float16)x.w };
    ((half4v*)d)[v] = h;
  }
}

// ---------------- cached K fp32 -> f16 linear convert ----------------
__global__ __launch_bounds__(256) void convert_K(
    const float* __restrict__ ck, _Float16* __restrict__ K)
{
  const long long nvec = (long long)NB * CL * DM / 4;
  const int pb = CL * DM / 4;
  for (long long v = (long long)blockIdx.x * blockDim.x + threadIdx.x; v < nvec;
       v += (long long)gridDim.x * blockDim.x) {
    int b = (int)(v / pb);
    long long r = v - (long long)b * pb;
    float4 x = ((const float4*)ck)[v];
    half4v hx = { (_Float16)x.x, (_Float16)x.y, (_Float16)x.z, (_Float16)x.w };
    ((half4v*)K)[(long long)b * (TT * DM / 4) + r] = hx;
  }
}

// ---------------- FUSED: QKV GEMM (bid<768) + cached-V transpose (bid>=768) ----------------
__global__ __launch_bounds__(512) void fused_pre(
    const _Float16* __restrict__ A0, const _Float16* __restrict__ A1,
    const _Float16* __restrict__ A2,
    const _Float16* __restrict__ W0, const _Float16* __restrict__ W1,
    const _Float16* __restrict__ W2,
    const float* __restrict__ b0, const float* __restrict__ b1,
    const float* __restrict__ b2,
    _Float16* __restrict__ Qp, _Float16* __restrict__ Kc,
    _Float16* __restrict__ Vt, const float* __restrict__ cv)
{
  __shared__ __align__(16) char smem[4 * 8192];

  const int bid = blockIdx.x;
  const int tid = threadIdx.x;

  if (bid < 768) {
    char* Abuf = smem;
    char* Wbuf = smem + 2 * 8192;
    const int bm = bid & 15, bn = (bid >> 4) & 15, z = bid >> 8;
    const _Float16* Ain = z == 0 ? A0 : z == 1 ? A1 : A2;
    const _Float16* W   = z == 0 ? W0 : z == 1 ? W1 : W2;
    const float* bias   = z == 0 ? b0 : z == 1 ? b1 : b2;

    const int wid = tid >> 6, lane = tid & 63;
    const int wm = wid >> 2, wn = wid & 3;
    const int lr = lane & 15, lg = lane >> 4;

    f32x4 acc[4][2];
#pragma unroll
    for (int i = 0; i < 4; ++i)
#pragma unroll
      for (int j = 0; j < 2; ++j) acc[i][j] = (f32x4){0.f, 0.f, 0.f, 0.f};

    size_t aoff, woff;
    {
      const int o = wid * 1024 + lane * 16;
      const int prow = o >> 7, pb = o & 127;
      const int lb = pb ^ ((prow & 7) << 4);
      const int r = (prow << 1) | (lb >> 6), c = lb & 63;
      aoff = (size_t)(bm * 128 + r) * 4096 + c;
      woff = (size_t)(bn * 128 + r) * 4096 + c;
    }

    auto stage = [&](int kt, int buf) {
      gl_lds16((const char*)Ain + aoff + kt * 64, Abuf + buf * 8192 + wid * 1024);
      gl_lds16((const char*)W + woff + kt * 64, Wbuf + buf * 8192 + wid * 1024);
    };
    auto lds_addr = [](const char* base, int r, int cb) -> const char* {
      return base + ((r >> 1) << 7) + ((((r & 1) << 6) | cb) ^ (((r >> 1) & 7) << 4));
    };
    auto compute = [&](int buf) {
      const char* ab = Abuf + buf * 8192;
      const char* wb = Wbuf + buf * 8192;
      half8 af[4], bf[2];
#pragma unroll
      for (int i = 0; i < 4; ++i)
        af[i] = *(const half8*)lds_addr(ab, wm * 64 + i * 16 + lr, lg << 4);
#pragma unroll
      for (int j = 0; j < 2; ++j)
        bf[j] = *(const half8*)lds_addr(wb, wn * 32 + j * 16 + lr, lg << 4);
#pragma unroll
      for (int i = 0; i < 4; ++i)
#pragma unroll
        for (int j = 0; j < 2; ++j)
          acc[i][j] = __builtin_amdgcn_mfma_f32_16x16x32_f16(af[i], bf[j], acc[i][j], 0, 0, 0);
    };

    const int NKT = DM / 32;
    stage(0, 0);
    __syncthreads();
    for (int kt = 0; kt < NKT; ++kt) {
      if (kt + 1 < NKT) stage(kt + 1, (kt + 1) & 1);
      compute(kt & 1);
      __syncthreads();
    }

    const float qscale = 0.08838834764831845f * 1.4426950408889634f;
#pragma unroll
    for (int i = 0; i < 4; ++i) {
      const int m0 = bm * 128 + wm * 64 + i * 16 + lg * 4;
#pragma unroll
      for (int j = 0; j < 2; ++j) {
        const int gn = bn * 128 + wn * 32 + j * 16 + lr;
        const float bb = bias[gn];
        if (z == 0) {
#pragma unroll
          for (int r = 0; r < 4; ++r)
            Qp[(size_t)(m0 + r) * DM + gn] = (_Float16)((acc[i][j][r] + bb) * qscale);
        } else if (z == 1) {
          const int b = m0 >> 9;
#pragma unroll
          for (int r = 0; r < 4; ++r)
            Kc[((size_t)b * TT + CL + ((m0 + r) & 511)) * DM + gn] =
                (_Float16)(acc[i][j][r] + bb);
        } else {
          half4v hv;
#pragma unroll
          for (int r = 0; r < 4; ++r) hv[r] = (_Float16)(acc[i][j][r] + bb);
          const int b = m0 >> 9, t = CL + (m0 & 511);
          const int h = gn >> 7, d = gn & 127;
          *(half4v*)&Vt[((size_t)(b * NH + h) * DH + d) * TT + t] = hv;
        }
      }
    }
  } else {
    _Float16 (*T)[136] = (_Float16(*)[136])smem;
    const int tv = bid - 768;
    const int b = tv / 896;
    const int rem = tv - b * 896;
    const int t0 = (rem % 56) * 64;
    const int dm0 = (rem / 56) * 128;
    {
      const int tr = tid >> 3, c0 = (tid & 7) * 16;
      const float* src = cv + ((size_t)b * CL + t0 + tr) * DM + dm0 + c0;
      float4 a0 = ((const float4*)src)[0];
      float4 a1 = ((const float4*)src)[1];
      float4 a2 = ((const float4*)src)[2];
      float4 a3 = ((const float4*)src)[3];
      half8 h0 = { (_Float16)a0.x, (_Float16)a0.y, (_Float16)a0.z, (_Float16)a0.w,
                   (_Float16)a1.x, (_Float16)a1.y, (_Float16)a1.z, (_Float16)a1.w };
      half8 h1 = { (_Float16)a2.x, (_Float16)a2.y, (_Float16)a2.z, (_Float16)a2.w,
                   (_Float16)a3.x, (_Float16)a3.y, (_Float16)a3.z, (_Float16)a3.w };
      *(half8*)&T[tr][c0] = h0;
      *(half8*)&T[tr][c0 + 8] = h1;
    }
    __syncthreads();
    {
      const int dl = tid >> 2, tc = (tid & 3) * 16;
      const int h = dm0 >> 7;
      half8 o0, o1;
#pragma unroll
      for (int i = 0; i < 8; ++i) o0[i] = T[tc + i][dl];
#pragma unroll
      for (int i = 0; i < 8; ++i) o1[i] = T[tc + 8 + i][dl];
      _Float16* dst = Vt + ((size_t)(b * NH + h) * DH + dl) * TT + t0 + tc;
      *(half8*)dst = o0;
      *(half8*)(dst + 8) = o1;
    }
  }
}

// ---------------- O-projection GEMM ----------------
__global__ __launch_bounds__(512, 4) void mm16o(
    const _Float16* __restrict__ Ain, const _Float16* __restrict__ W,
    const float* __restrict__ bias, float* __restrict__ Co)
{
  __shared__ __align__(16) char smem[4 * 8192];
  char* Abuf = smem;
  char* Wbuf = smem + 2 * 8192;

  const int tid = threadIdx.x;
  const int bm = blockIdx.x, bn = blockIdx.y;
  const int wid = tid >> 6, lane = tid & 63;
  const int wm = wid >> 2, wn = wid & 3;
  const int lr = lane & 15, lg = lane >> 4;

  f32x4 acc[4][2];
#pragma unroll
  for (int i = 0; i < 4; ++i)
#pragma unroll
    for (int j = 0; j < 2; ++j) acc[i][j] = (f32x4){0.f, 0.f, 0.f, 0.f};

  size_t aoff, woff;
  {
    const int o = wid * 1024 + lane * 16;
    const int prow = o >> 7, pb = o & 127;
    const int lb = pb ^ ((prow & 7) << 4);
    const int r = (prow << 1) | (lb >> 6), c = lb & 63;
    aoff = (size_t)(bm * 128 + r) * 4096 + c;
    woff = (size_t)(bn * 128 + r) * 4096 + c;
  }

  auto stage = [&](int kt, int buf) {
    gl_lds16((const char*)Ain + aoff + kt * 64, Abuf + buf * 8192 + wid * 1024);
    gl_lds16((const char*)W + woff + kt * 64, Wbuf + buf * 8192 + wid * 1024);
  };
  auto lds_addr = [](const char* base, int r, int cb) -> const char* {
    return base + ((r >> 1) << 7) + ((((r & 1) << 6) | cb) ^ (((r >> 1) & 7) << 4));
  };
  auto compute = [&](int buf) {
    const char* ab = Abuf + buf * 8192;
    const char* wb = Wbuf + buf * 8192;
    half8 af[4], bf[2];
#pragma unroll
    for (int i = 0; i < 4; ++i)
      af[i] = *(const half8*)lds_addr(ab, wm * 64 + i * 16 + lr, lg << 4);
#pragma unroll
    for (int j = 0; j < 2; ++j)
      bf[j] = *(const half8*)lds_addr(wb, wn * 32 + j * 16 + lr, lg << 4);
#pragma unroll
    for (int i = 0; i < 4; ++i)
#pragma unroll
      for (int j = 0; j < 2; ++j)
        acc[i][j] = __builtin_amdgcn_mfma_f32_16x16x32_f16(af[i], bf[j], acc[i][j], 0, 0, 0);
  };

  const int NKT = DM / 32;
  stage(0, 0);
  __syncthreads();
  for (int kt = 0; kt < NKT; ++kt) {
    if (kt + 1 < NKT) stage(kt + 1, (kt + 1) & 1);
    compute(kt & 1);
    __syncthreads();
  }

#pragma unroll
  for (int i = 0; i < 4; ++i) {
    const int m0 = bm * 128 + wm * 64 + i * 16 + lg * 4;
#pragma unroll
    for (int j = 0; j < 2; ++j) {
      const int gn = bn * 128 + wn * 32 + j * 16 + lr;
      const float bb = bias[gn];
#pragma unroll
      for (int r = 0; r < 4; ++r)
        Co[(size_t)(m0 + r) * DM + gn] = acc[i][j][r] + bb;
    }
  }
}

// ================= attn v9: KVB=32, kv-split x4, 48KB LDS, 2 blocks/CU =================
// 512 blocks (b,h,qb0..1,part0..3), 512 thr = 8 waves x 32 q. Same-tile order.
// K dbuf 16K + V dbuf 16K (paired-line swizzle) + Ps 16K = 48KB; VGPR target <=128.
__global__ __launch_bounds__(512) void attn_kernel4(
    const _Float16* __restrict__ Qp, const _Float16* __restrict__ Kc,
    const _Float16* __restrict__ Vt, _Float16* __restrict__ O0,
    _Float16* __restrict__ O1, _Float16* __restrict__ O2,
    _Float16* __restrict__ O3, float2* __restrict__ ml)
{
  __shared__ _Float16 Ks[2][32 * 128];   // 8KB x2
  __shared__ _Float16 VTs[2][64 * 64];   // 8KB x2, 64 lines x 128B
  __shared__ _Float16 Ps[8][32 * 32];    // 2KB/wave

  const int tid = threadIdx.x;
  const int lin = blockIdx.x;
  const int xcd = lin & 7, slot = lin >> 3;       // 512 blocks
  const int pair = xcd * 8 + (slot >> 3);         // (b,h) 0..63
  const int rem = slot & 7;
  const int qb = rem >> 2, part = rem & 3;        // qb 0..1, part 0..3
  const int b = pair >> 4, h = pair & 15;

  const int wid = tid >> 6, lane = tid & 63;
  const int lr = lane & 15, lg = lane >> 4;
  const int qw = qb * 256 + wid * 32;

  half8 qf[2][4];
#pragma unroll
  for (int qs = 0; qs < 2; ++qs)
#pragma unroll
    for (int kk = 0; kk < 4; ++kk)
      qf[qs][kk] = *(const half8*)&Qp[(size_t)(b * SQ + qw + qs * 16 + lr) * DM +
                                      h * DH + kk * 32 + lg * 8];

  f32x4 zero = {0.f, 0.f, 0.f, 0.f};
  f32x4 acc[8][2];
#pragma unroll
  for (int d = 0; d < 8; ++d)
#pragma unroll
    for (int qs = 0; qs < 2; ++qs) acc[d][qs] = zero;
  float m_run[2] = {-1e30f, -1e30f}, l_run[2] = {0.f, 0.f};

  const int nt_full = (CL + qb * 256 + 256) / 32;   // 120 or 128 (both %4==0)
  const int quarter = nt_full >> 2;
  const int tbeg = part * quarter;
  const int nt = quarter;

  // staging sources (pre-unswizzled): 1 K granule + 1 V granule per thread
  int ksrc, vsrc;
  {
    const int r = tid >> 4, pg = tid & 15;
    ksrc = r * DM + (pg ^ (r & 7)) * 8;
  }
  {
    const int line = tid >> 3, slot8 = tid & 7;
    const int un = slot8 ^ (line & 7);
    const int d = (line << 1) | (un >> 2), g = un & 3;
    vsrc = d * TT + g * 8;
  }
  const _Float16* Kb = Kc + (size_t)b * TT * DM + h * DH;
  const _Float16* Vb = Vt + (size_t)(b * NH + h) * DH * TT;

  auto stage = [&](int tt, int buf) {
    const int t0 = (tbeg + tt) * 32;
    gl_lds16(Kb + (size_t)t0 * DM + ksrc, &Ks[buf][tid * 8]);
    gl_lds16(Vb + t0 + vsrc, &VTs[buf][tid * 8]);
  };

  f32x4 s[2][2];

  stage(0, 0);
  __syncthreads();

  for (int t = 0; t < nt; ++t) {
    const int cur = t & 1;
    if (t + 1 < nt) stage(t + 1, cur ^ 1);

    // S^T = K Q^T (32t x 32q per wave)
#pragma unroll
    for (int j = 0; j < 2; ++j)
#pragma unroll
      for (int qs = 0; qs < 2; ++qs) s[j][qs] = zero;
#pragma unroll
    for (int kk = 0; kk < 4; ++kk)
#pragma unroll
      for (int j = 0; j < 2; ++j) {
        half8 kb = *(const half8*)&Ks[cur][KSW(j * 16 + lr, kk * 32 + lg * 8)];
        s[j][0] = __builtin_amdgcn_mfma_f32_16x16x32_f16(kb, qf[0][kk], s[j][0], 0, 0, 0);
        s[j][1] = __builtin_amdgcn_mfma_f32_16x16x32_f16(kb, qf[1][kk], s[j][1], 0, 0, 0);
      }

    // causal mask: only part 3 can mask
    if (part == 3) {
      const int t0 = (tbeg + t) * 32;
      if (t0 + 31 > CL + qw) {
#pragma unroll
        for (int j = 0; j < 2; ++j)
#pragma unroll
          for (int qs = 0; qs < 2; ++qs)
#pragma unroll
            for (int r = 0; r < 4; ++r)
              if (t0 + j * 16 + lg * 4 + r > CL + qw + qs * 16 + lr) s[j][qs][r] = -1e30f;
      }
    }

    // online softmax (defer-max), per-lane partial l
    float mt[2];
#pragma unroll
    for (int qs = 0; qs < 2; ++qs) {
      float m = s[0][qs][0];
#pragma unroll
      for (int j = 0; j < 2; ++j)
#pragma unroll
        for (int r = 0; r < 4; ++r) m = fmaxf(m, s[j][qs][r]);
      mt[qs] = m;
    }
    if (!__all(mt[0] <= m_run[0] + 10.0f && mt[1] <= m_run[1] + 10.0f)) {
#pragma unroll
      for (int qs = 0; qs < 2; ++qs) {
        float m = fmaxf(mt[qs], __shfl_xor(mt[qs], 16));
        m = fmaxf(m, __shfl_xor(m, 32));
        const float mn = fmaxf(m_run[qs], m);
        const float fsc = exp2f(m_run[qs] - mn);
        m_run[qs] = mn;
        l_run[qs] *= fsc;
#pragma unroll
        for (int d = 0; d < 8; ++d)
#pragma unroll
          for (int r = 0; r < 4; ++r) acc[d][qs][r] *= fsc;
      }
    }
#pragma unroll
    for (int qs = 0; qs < 2; ++qs) {
      float ps = 0.f;
#pragma unroll
      for (int j = 0; j < 2; ++j) {
        float p0 = exp2f(s[j][qs][0] - m_run[qs]);
        float p1 = exp2f(s[j][qs][1] - m_run[qs]);
        float p2 = exp2f(s[j][qs][2] - m_run[qs]);
        float p3 = exp2f(s[j][qs][3] - m_run[qs]);
        ps += (p0 + p1) + (p2 + p3);
        half4v hp = { (_Float16)p0, (_Float16)p1, (_Float16)p2, (_Float16)p3 };
        *(half4v*)&Ps[wid][PSW2(qs * 16 + lr, j * 16 + lg * 4)] = hp;
      }
      l_run[qs] += ps;
    }

    // O^T += V^T P^T  (K = 32 = whole tile)
    {
      half8 pf0 = *(const half8*)&Ps[wid][PSW2(lr, lg * 8)];
      half8 pf1 = *(const half8*)&Ps[wid][PSW2(16 + lr, lg * 8)];
#pragma unroll
      for (int d = 0; d < 8; ++d) {
        half8 vf = *(const half8*)&VTs[cur][VAD(d * 16 + lr, lg)];
        acc[d][0] = __builtin_amdgcn_mfma_f32_16x16x32_f16(vf, pf0, acc[d][0], 0, 0, 0);
        acc[d][1] = __builtin_amdgcn_mfma_f32_16x16x32_f16(vf, pf1, acc[d][1], 0, 0, 0);
      }
    }

    __syncthreads();
  }

  _Float16* Od = part == 0 ? O0 : part == 1 ? O1 : part == 2 ? O2 : O3;
#pragma unroll
  for (int qs = 0; qs < 2; ++qs) {
    float lt = l_run[qs] + __shfl_xor(l_run[qs], 16);
    lt += __shfl_xor(lt, 32);
    const float inv = 1.0f / lt;
#pragma unroll
    for (int d = 0; d < 8; ++d) {
      half4v hv;
#pragma unroll
      for (int r = 0; r < 4; ++r) hv[r] = (_Float16)(acc[d][qs][r] * inv);
      *(half4v*)&Od[(size_t)(b * SQ + qw + qs * 16 + lr) * DM + h * DH + d * 16 + lg * 4] = hv;
    }
    if (lg == 0) {
      float2 e; e.x = m_run[qs]; e.y = lt;
      ml[part * (64 * SQ) + ((b * NH + h) * SQ) + qw + qs * 16 + lr] = e;
    }
  }
}

// ---------------- 4-way combine ----------------
__global__ __launch_bounds__(256) void combine4(
    _Float16* __restrict__ AO, const _Float16* __restrict__ O1,
    const _Float16* __restrict__ O2, const _Float16* __restrict__ O3,
    const float2* __restrict__ ml)
{
  const int idx = blockIdx.x * 256 + threadIdx.x;
  const int row = idx >> 8;
  const int col0 = (idx & 255) * 8;
  const int b = row >> 9, q = row & 511, h = col0 >> 7;
  const int base = (b * NH + h) * SQ + q;
  float2 e0 = ml[base];
  float2 e1 = ml[64 * SQ + base];
  float2 e2 = ml[2 * 64 * SQ + base];
  float2 e3 = ml[3 * 64 * SQ + base];
  float m = fmaxf(fmaxf(e0.x, e1.x), fmaxf(e2.x, e3.x));
  float w0 = e0.y * exp2f(e0.x - m);
  float w1 = e1.y * exp2f(e1.x - m);
  float w2 = e2.y * exp2f(e2.x - m);
  float w3 = e3.y * exp2f(e3.x - m);
  const float inv = 1.0f / (((w0 + w1) + (w2 + w3)));
  w0 *= inv; w1 *= inv; w2 *= inv; w3 *= inv;
  const size_t o = (size_t)row * DM + col0;
  half8 a = *(const half8*)&AO[o];
  half8 c1 = *(const half8*)&O1[o];
  half8 c2 = *(const half8*)&O2[o];
  half8 c3 = *(const half8*)&O3[o];
  half8 r;
#pragma unroll
  for (int i = 0; i < 8; ++i)
    r[i] = (_Float16)(w0 * (float)a[i] + w1 * (float)c1[i] +
                      w2 * (float)c2[i] + w3 * (float)c3[i]);
  *(half8*)&AO[o] = r;
}

// ================= fallback: R12 attn (kv-split x2) + combine2 =================
__global__ __launch_bounds__(512) void attn_kernel2(
    const _Float16* __restrict__ Qp, const _Float16* __restrict__ Kc,
    const _Float16* __restrict__ Vt, _Float16* __restrict__ O0,
    _Float16* __restrict__ O1, float2* __restrict__ ml)
{
  __shared__ _Float16 Ks[2][64 * 128];
  __shared__ _Float16 VTs[3][128 * 64];
  __shared__ _Float16 Ps[8][32 * 64];

  const int tid = threadIdx.x;
  const int lin = blockIdx.x;
  const int xcd = lin & 7, slot = lin >> 3;
  const int pair = xcd * 8 + (slot >> 2);
  const int rem = slot & 3;
  const int qb = rem >> 1, part = rem & 1;
  const int b = pair >> 4, h = pair & 15;

  const int wid = tid >> 6, lane = tid & 63;
  const int lr = lane & 15, lg = lane >> 4;
  const int qw = qb * 256 + wid * 32;

  half8 qf[2][4];
#pragma unroll
  for (int qs = 0; qs < 2; ++qs)
#pragma unroll
    for (int kk = 0; kk < 4; ++kk)
      qf[qs][kk] = *(const half8*)&Qp[(size_t)(b * SQ + qw + qs * 16 + lr) * DM +
                                      h * DH + kk * 32 + lg * 8];

  f32x4 zero = {0.f, 0.f, 0.f, 0.f};
  f32x4 acc[8][2];
#pragma unroll
  for (int d = 0; d < 8; ++d)
#pragma unroll
    for (int qs = 0; qs < 2; ++qs) acc[d][qs] = zero;
  float m_run[2] = {-1e30f, -1e30f}, l_run[2] = {0.f, 0.f};

  const int nt_full = (CL + qb * 256 + 256) / 64;
  const int halfn = nt_full >> 1;
  const int tbeg = part ? halfn : 0;
  const int nt = part ? (nt_full - halfn) : halfn;

  int ksrc[2], vsrc[2];
#pragma unroll
  for (int c = 0; c < 2; ++c) {
    const int p = c * 512 + wid * 64 + lane;
    { const int r = p >> 4, pg = p & 15, gc = pg ^ (r & 7);
      ksrc[c] = r * DM + gc * 8; }
    { const int d = p >> 3, pg = p & 7, gt = pg ^ (d & 7);
      vsrc[c] = d * TT + gt * 8; }
  }
  const _Float16* Kb = Kc + (size_t)b * TT * DM + h * DH;
  const _Float16* Vb = Vt + (size_t)(b * NH + h) * DH * TT;

  auto stage = [&](int tt, int kbuf, int vbuf) {
    const int t0 = (tbeg + tt) * 64;
#pragma unroll
    for (int c = 0; c < 2; ++c)
      gl_lds16(Kb + (size_t)t0 * DM + ksrc[c], &Ks[kbuf][(c * 512 + wid * 64) * 8]);
#pragma unroll
    for (int c = 0; c < 2; ++c)
      gl_lds16(Vb + t0 + vsrc[c], &VTs[vbuf][(c * 512 + wid * 64) * 8]);
  };

  auto qk = [&](int kbuf, f32x4 (*s)[2]) {
#pragma unroll
    for (int j = 0; j < 4; ++j)
#pragma unroll
      for (int qs = 0; qs < 2; ++qs) s[j][qs] = zero;
#pragma unroll
    for (int kk = 0; kk < 4; ++kk)
#pragma unroll
      for (int j = 0; j < 4; ++j) {
        half8 kb = *(const half8*)&Ks[kbuf][KSW(j * 16 + lr, kk * 32 + lg * 8)];
        s[j][0] = __builtin_amdgcn_mfma_f32_16x16x32_f16(kb, qf[0][kk], s[j][0], 0, 0, 0);
        s[j][1] = __builtin_amdgcn_mfma_f32_16x16x32_f16(kb, qf[1][kk], s[j][1], 0, 0, 0);
      }
  };

  auto mask_s = [&](int t0, f32x4 (*s)[2]) {
    if (part && t0 + 63 > CL + qw) {
#pragma unroll
      for (int j = 0; j < 4; ++j)
#pragma unroll
        for (int qs = 0; qs < 2; ++qs)
#pragma unroll
          for (int r = 0; r < 4; ++r)
            if (t0 + j * 16 + lg * 4 + r > CL + qw + qs * 16 + lr) s[j][qs][r] = -1e30f;
    }
  };

  auto softmax_step = [&](f32x4 (*s)[2]) {
    float mt[2];
#pragma unroll
    for (int qs = 0; qs < 2; ++qs) {
      float m = s[0][qs][0];
#pragma unroll
      for (int j = 0; j < 4; ++j)
#pragma unroll
        for (int r = 0; r < 4; ++r) m = fmaxf(m, s[j][qs][r]);
      mt[qs] = m;
    }
    if (!__all(mt[0] <= m_run[0] + 10.0f && mt[1] <= m_run[1] + 10.0f)) {
#pragma unroll
      for (int qs = 0; qs < 2; ++qs) {
        float m = fmaxf(mt[qs], __shfl_xor(mt[qs], 16));
        m = fmaxf(m, __shfl_xor(m, 32));
        const float mn = fmaxf(m_run[qs], m);
        const float fsc = exp2f(m_run[qs] - mn);
        m_run[qs] = mn;
        l_run[qs] *= fsc;
#pragma unroll
        for (int d = 0; d < 8; ++d)
#pragma unroll
          for (int r = 0; r < 4; ++r) acc[d][qs][r] *= fsc;
      }
    }
#pragma unroll
    for (int qs = 0; qs < 2; ++qs) {
      float ps = 0.f;
#pragma unroll
      for (int j = 0; j < 4; ++j) {
        float p0 = exp2f(s[j][qs][0] - m_run[qs]);
        float p1 = exp2f(s[j][qs][1] - m_run[qs]);
        float p2 = exp2f(s[j][qs][2] - m_run[qs]);
        float p3 = exp2f(s[j][qs][3] - m_run[qs]);
        ps += (p0 + p1) + (p2 + p3);
        half4v hp = { (_Float16)p0, (_Float16)p1, (_Float16)p2, (_Float16)p3 };
        *(half4v*)&Ps[wid][PSW(qs * 16 + lr, j * 16 + lg * 4)] = hp;
      }
      l_run[qs] += ps;
    }
  };

  auto pv = [&](int vbuf) {
#pragma unroll
    for (int kk = 0; kk < 2; ++kk) {
      half8 pf0 = *(const half8*)&Ps[wid][PSW(lr, kk * 32 + lg * 8)];
      half8 pf1 = *(const half8*)&Ps[wid][PSW(16 + lr, kk * 32 + lg * 8)];
#pragma unroll
      for (int d = 0; d < 8; ++d) {
        half8 vf = *(const half8*)&VTs[vbuf][VSW(d * 16 + lr, kk * 32 + lg * 8)];
        acc[d][0] = __builtin_amdgcn_mfma_f32_16x16x32_f16(vf, pf0, acc[d][0], 0, 0, 0);
        acc[d][1] = __builtin_amdgcn_mfma_f32_16x16x32_f16(vf, pf1, acc[d][1], 0, 0, 0);
      }
    }
  };

  f32x4 sp[4][2], sc[4][2];

  stage(0, 0, 0);
  __syncthreads();
  stage(1, 1, 1);
  qk(0, sp);
  mask_s(tbeg * 64, sp);

  for (int t = 1; t < nt; ++t) {
    __syncthreads();
    if (t + 1 < nt) stage(t + 1, (t + 1) & 1, (t + 1) % 3);
    qk(t & 1, sc);
    softmax_step(sp);
    pv((t - 1) % 3);
    mask_s((tbeg + t) * 64, sc);
#pragma unroll
    for (int j = 0; j < 4; ++j)
#pragma unroll
      for (int qs = 0; qs < 2; ++qs) sp[j][qs] = sc[j][qs];
  }
  softmax_step(sp);
  pv((nt - 1) % 3);

  _Float16* Od = part ? O1 : O0;
#pragma unroll
  for (int qs = 0; qs < 2; ++qs) {
    float lt = l_run[qs] + __shfl_xor(l_run[qs], 16);
    lt += __shfl_xor(lt, 32);
    const float inv = 1.0f / lt;
#pragma unroll
    for (int d = 0; d < 8; ++d) {
      half4v hv;
#pragma unroll
      for (int r = 0; r < 4; ++r) hv[r] = (_Float16)(acc[d][qs][r] * inv);
      *(half4v*)&Od[(size_t)(b * SQ + qw + qs * 16 + lr) * DM + h * DH + d * 16 + lg * 4] = hv;
    }
    if (lg == 0) {
      float2 e; e.x = m_run[qs]; e.y = lt;
      ml[part * (64 * SQ) + ((b * NH + h) * SQ) + qw + qs * 16 + lr] = e;
    }
  }
}

__global__ __launch_bounds__(256) void combine2(
    _Float16* __restrict__ AO, const _Float16* __restrict__ O1,
    const float2* __restrict__ ml)
{
  const int idx = blockIdx.x * 256 + threadIdx.x;
  const int row = idx >> 8;
  const int col0 = (idx & 255) * 8;
  const int b = row >> 9, q = row & 511, h = col0 >> 7;
  const float2 e0 = ml[(b * NH + h) * SQ + q];
  const float2 e1 = ml[64 * SQ + (b * NH + h) * SQ + q];
  const float m = fmaxf(e0.x, e1.x);
  float w0 = e0.y * exp2f(e0.x - m);
  float w1 = e1.y * exp2f(e1.x - m);
  const float inv = 1.0f / (w0 + w1);
  w0 *= inv; w1 *= inv;
  const size_t o = (size_t)row * DM + col0;
  half8 a = *(const half8*)&AO[o];
  half8 c = *(const half8*)&O1[o];
  half8 r;
#pragma unroll
  for (int i = 0; i < 8; ++i)
    r[i] = (_Float16)(w0 * (float)a[i] + w1 * (float)c[i]);
  *(half8*)&AO[o] = r;
}

extern "C" void kernel_launch(void* const* d_in, const int* in_sizes, int n_in,
                              void* d_out, int out_size, void* d_ws, size_t ws_size,
                              hipStream_t stream) {
  const float* query = (const float*)d_in[0];
  const float* key   = (const float*)d_in[1];
  const float* value = (const float*)d_in[2];
  const float* ck    = (const float*)d_in[3];
  const float* cv    = (const float*)d_in[4];
  const float* wq = (const float*)d_in[5];
  const float* bq = (const float*)d_in[6];
  const float* wk = (const float*)d_in[7];
  const float* bk = (const float*)d_in[8];
  const float* wv = (const float*)d_in[9];
  const float* bv = (const float*)d_in[10];
  const float* wo = (const float*)d_in[11];
  const float* bo = (const float*)d_in[12];

  char* ws = (char*)d_ws;
  _Float16* Kc = (_Float16*)ws;                 // 64 MiB
  _Float16* Vt = (_Float16*)(ws + 67108864);    // 64 MiB
  _Float16* Qp = (_Float16*)(ws + 134217728);   // 8 MiB
  _Float16* AO = (_Float16*)(ws + 142606336);   // 8 MiB

  _Float16* qh = AO;
  _Float16* kh = (_Float16*)d_out;
  _Float16* vh = (_Float16*)((char*)d_out + 8388608);
  _Float16* wqh = Kc;
  _Float16* wkh = (_Float16*)(ws + 16777216);
  _Float16* wvh = (_Float16*)(ws + 33554432);
  _Float16* woh = Qp;

  cvt_f16<<<dim3(512, 6), 256, 0, stream>>>(
      query, key, value, wq, wk, wv, qh, kh, vh, wqh, wkh, wvh);
  fused_pre<<<768 + 3584, 512, 0, stream>>>(
      qh, kh, vh, wqh, wkh, wvh, bq, bk, bv, Qp, Kc, Vt, cv);
  convert_K<<<2048, 256, 0, stream>>>(ck, Kc);

  const bool big = ws_size >= (size_t)153 * 1024 * 1024;
  if (big) {
    _Float16* O1s = (_Float16*)d_out;                       // 8 MiB
    _Float16* O2s = (_Float16*)((char*)d_out + 8388608);    // 8 MiB
    _Float16* O3s = (_Float16*)(ws + 150994944);            // 8 MiB at ws+144MiB
    float2* mls = (float2*)(ws + 159383552);                // 1 MiB at ws+152MiB
    attn_kernel4<<<512, 512, 0, stream>>>(Qp, Kc, Vt, AO, O1s, O2s, O3s, mls);
    combine4<<<2048, 256, 0, stream>>>(AO, O1s, O2s, O3s, mls);
  } else {
    _Float16* O1s = (_Float16*)d_out;
    float2* mls = (float2*)((char*)d_out + 8388608);
    attn_kernel2<<<256, 512, 0, stream>>>(Qp, Kc, Vt, AO, O1s, mls);
    combine2<<<2048, 256, 0, stream>>>(AO, O1s, mls);
  }

  cvt_f16_one<<<512, 256, 0, stream>>>(wo, woh);
  mm16o<<<dim3(16, 16), 512, 0, stream>>>(AO, woh, bo, (float*)d_out);
}

// Round 14
// 332.453 us; speedup vs baseline: 1.0193x; 1.0193x over previous
//
#include <hip/hip_runtime.h>

typedef _Float16 half8 __attribute__((ext_vector_type(8)));
typedef _Float16 half4v __attribute__((ext_vector_type(4)));
typedef float f32x4 __attribute__((ext_vector_type(4)));

#define NB 4
#define SQ 512
#define CL 3584
#define TT 4096
#define DM 2048
#define NH 16
#define DH 128

// XOR swizzles on half-index (attn LDS)
#define KSW(row, col) ((((row) * 128) + (col)) ^ ((((row) & 7) << 3)))
#define VSW(row, col) ((((row) * 64) + (col)) ^ ((((row) & 7) << 3)))
#define PSW(row, col) ((((row) * 64) + (col)) ^ ((((row) & 7) << 3)))

__device__ __forceinline__ void gl_lds16(const void* g, void* l) {
  __builtin_amdgcn_global_load_lds(
      (const __attribute__((address_space(1))) unsigned int*)g,
      (__attribute__((address_space(3))) unsigned int*)l, 16, 0, 0);
}

// ---------------- fp32 -> f16 dense convert, 3 slices (q,k,v inputs) ----------------
__global__ __launch_bounds__(256) void cvt_f16(
    const float* __restrict__ s0, const float* __restrict__ s1, const float* __restrict__ s2,
    _Float16* __restrict__ d0, _Float16* __restrict__ d1, _Float16* __restrict__ d2)
{
  const int z = blockIdx.y;
  const float* s = z == 0 ? s0 : z == 1 ? s1 : s2;
  _Float16* d = z == 0 ? d0 : z == 1 ? d1 : d2;
  const int n4 = DM * DM / 4;
  for (int v = blockIdx.x * blockDim.x + threadIdx.x; v < n4;
       v += gridDim.x * blockDim.x) {
    float4 x = ((const float4*)s)[v];
    half4v h = { (_Float16)x.x, (_Float16)x.y, (_Float16)x.z, (_Float16)x.w };
    ((half4v*)d)[v] = h;
  }
}

__global__ __launch_bounds__(256) void cvt_f16_one(
    const float* __restrict__ s, _Float16* __restrict__ d)
{
  const int n4 = DM * DM / 4;
  for (int v = blockIdx.x * blockDim.x + threadIdx.x; v < n4;
       v += gridDim.x * blockDim.x) {
    float4 x = ((const float4*)s)[v];
    half4v h = { (_Float16)x.x, (_Float16)x.y, (_Float16)x.z, (_Float16)x.w };
    ((half4v*)d)[v] = h;
  }
}

// ---- FUSED: QKV GEMM (bid<768) + cached-V transpose (bid<4352) + cached-K cvt (rest) ----
// GEMM: A (f16) via gl_lds; W read as fp32 with async reg-stage -> cvt -> ds_write (T14).
// transV / convK: pure-BW blocks that overlap the compute-bound GEMM blocks.
__global__ __launch_bounds__(512) void fused_pre(
    const _Float16* __restrict__ A0, const _Float16* __restrict__ A1,
    const _Float16* __restrict__ A2,
    const float* __restrict__ Wq, const float* __restrict__ Wk,
    const float* __restrict__ Wv,
    const float* __restrict__ b0, const float* __restrict__ b1,
    const float* __restrict__ b2,
    _Float16* __restrict__ Qp, _Float16* __restrict__ Kc,
    _Float16* __restrict__ Vt, const float* __restrict__ cv,
    const float* __restrict__ ck)
{
  __shared__ __align__(16) char smem[4 * 8192];

  const int bid = blockIdx.x;
  const int tid = threadIdx.x;

  if (bid < 768) {
    // ---------------- QKV GEMM ----------------
    char* Abuf = smem;
    char* Wbuf = smem + 2 * 8192;
    const int bm = bid & 15, bn = (bid >> 4) & 15, z = bid >> 8;
    const _Float16* Ain = z == 0 ? A0 : z == 1 ? A1 : A2;
    const float* Wf     = z == 0 ? Wq : z == 1 ? Wk : Wv;
    const float* bias   = z == 0 ? b0 : z == 1 ? b1 : b2;

    const int wid = tid >> 6, lane = tid & 63;
    const int wm = wid >> 2, wn = wid & 3;
    const int lr = lane & 15, lg = lane >> 4;

    f32x4 acc[4][2];
#pragma unroll
    for (int i = 0; i < 4; ++i)
#pragma unroll
      for (int j = 0; j < 2; ++j) acc[i][j] = (f32x4){0.f, 0.f, 0.f, 0.f};

    size_t aoff, woff32;
    {
      const int o = wid * 1024 + lane * 16;
      const int prow = o >> 7, pb = o & 127;
      const int lb = pb ^ ((prow & 7) << 4);
      const int r = (prow << 1) | (lb >> 6), c = lb & 63;   // c: f16-byte 0/16/32/48
      aoff = (size_t)(bm * 128 + r) * 4096 + c;
      woff32 = (size_t)(bn * 128 + r) * 8192 + (size_t)c * 2;
    }
    const int ldst = wid * 1024 + lane * 16;

    float4 wr0, wr1;
    auto stage_load = [&](int kt) {
      gl_lds16((const char*)Ain + aoff + kt * 64, Abuf + ((kt & 1) * 8192) + ldst);
      const char* wp = (const char*)Wf + woff32 + (size_t)kt * 128;
      wr0 = *(const float4*)wp;
      wr1 = *(const float4*)(wp + 16);
    };
    auto stage_write = [&](int buf) {
      int u0 = __builtin_bit_cast(int, __builtin_amdgcn_cvt_pkrtz(wr0.x, wr0.y));
      int u1 = __builtin_bit_cast(int, __builtin_amdgcn_cvt_pkrtz(wr0.z, wr0.w));
      int u2 = __builtin_bit_cast(int, __builtin_amdgcn_cvt_pkrtz(wr1.x, wr1.y));
      int u3 = __builtin_bit_cast(int, __builtin_amdgcn_cvt_pkrtz(wr1.z, wr1.w));
      uint4 u = { (unsigned)u0, (unsigned)u1, (unsigned)u2, (unsigned)u3 };
      *(uint4*)(Wbuf + buf * 8192 + ldst) = u;
    };
    auto lds_addr = [](const char* base, int r, int cb) -> const char* {
      return base + ((r >> 1) << 7) + ((((r & 1) << 6) | cb) ^ (((r >> 1) & 7) << 4));
    };
    auto compute = [&](int buf) {
      const char* ab = Abuf + buf * 8192;
      const char* wb = Wbuf + buf * 8192;
      half8 af[4], bf[2];
#pragma unroll
      for (int i = 0; i < 4; ++i)
        af[i] = *(const half8*)lds_addr(ab, wm * 64 + i * 16 + lr, lg << 4);
#pragma unroll
      for (int j = 0; j < 2; ++j)
        bf[j] = *(const half8*)lds_addr(wb, wn * 32 + j * 16 + lr, lg << 4);
#pragma unroll
      for (int i = 0; i < 4; ++i)
#pragma unroll
        for (int j = 0; j < 2; ++j)
          acc[i][j] = __builtin_amdgcn_mfma_f32_16x16x32_f16(af[i], bf[j], acc[i][j], 0, 0, 0);
    };

    const int NKT = DM / 32;
    stage_load(0);
    stage_write(0);
    __syncthreads();
    for (int kt = 0; kt < NKT; ++kt) {
      if (kt + 1 < NKT) stage_load(kt + 1);
      compute(kt & 1);
      if (kt + 1 < NKT) stage_write((kt + 1) & 1);
      __syncthreads();
    }

    const float qscale = 0.08838834764831845f * 1.4426950408889634f;
#pragma unroll
    for (int i = 0; i < 4; ++i) {
      const int m0 = bm * 128 + wm * 64 + i * 16 + lg * 4;
#pragma unroll
      for (int j = 0; j < 2; ++j) {
        const int gn = bn * 128 + wn * 32 + j * 16 + lr;
        const float bb = bias[gn];
        if (z == 0) {
#pragma unroll
          for (int r = 0; r < 4; ++r)
            Qp[(size_t)(m0 + r) * DM + gn] = (_Float16)((acc[i][j][r] + bb) * qscale);
        } else if (z == 1) {
          const int b = m0 >> 9;
#pragma unroll
          for (int r = 0; r < 4; ++r)
            Kc[((size_t)b * TT + CL + ((m0 + r) & 511)) * DM + gn] =
                (_Float16)(acc[i][j][r] + bb);
        } else {
          half4v hv;
#pragma unroll
          for (int r = 0; r < 4; ++r) hv[r] = (_Float16)(acc[i][j][r] + bb);
          const int b = m0 >> 9, t = CL + (m0 & 511);
          const int h = gn >> 7, d = gn & 127;
          *(half4v*)&Vt[((size_t)(b * NH + h) * DH + d) * TT + t] = hv;
        }
      }
    }
  } else if (bid < 768 + 3584) {
    // ---------------- cached V transpose: 64t x 128dm tile ----------------
    _Float16 (*T)[136] = (_Float16(*)[136])smem;
    const int tv = bid - 768;
    const int b = tv / 896;
    const int rem = tv - b * 896;
    const int t0 = (rem % 56) * 64;
    const int dm0 = (rem / 56) * 128;
    {
      const int tr = tid >> 3, c0 = (tid & 7) * 16;
      const float* src = cv + ((size_t)b * CL + t0 + tr) * DM + dm0 + c0;
      float4 a0 = ((const float4*)src)[0];
      float4 a1 = ((const float4*)src)[1];
      float4 a2 = ((const float4*)src)[2];
      float4 a3 = ((const float4*)src)[3];
      half8 h0 = { (_Float16)a0.x, (_Float16)a0.y, (_Float16)a0.z, (_Float16)a0.w,
                   (_Float16)a1.x, (_Float16)a1.y, (_Float16)a1.z, (_Float16)a1.w };
      half8 h1 = { (_Float16)a2.x, (_Float16)a2.y, (_Float16)a2.z, (_Float16)a2.w,
                   (_Float16)a3.x, (_Float16)a3.y, (_Float16)a3.z, (_Float16)a3.w };
      *(half8*)&T[tr][c0] = h0;
      *(half8*)&T[tr][c0 + 8] = h1;
    }
    __syncthreads();
    {
      const int dl = tid >> 2, tc = (tid & 3) * 16;
      const int h = dm0 >> 7;
      half8 o0, o1;
#pragma unroll
      for (int i = 0; i < 8; ++i) o0[i] = T[tc + i][dl];
#pragma unroll
      for (int i = 0; i < 8; ++i) o1[i] = T[tc + 8 + i][dl];
      _Float16* dst = Vt + ((size_t)(b * NH + h) * DH + dl) * TT + t0 + tc;
      *(half8*)dst = o0;
      *(half8*)(dst + 8) = o1;
    }
  } else {
    // ---------------- cached K fp32 -> f16 (grid-stride over 1024 blocks) ----------------
    const int cb = bid - (768 + 3584);            // 0..1023
    const long long nvec = (long long)NB * CL * DM / 4;   // 7,340,032
    const int pb = CL * DM / 4;
    const long long stride = 1024LL * 512;
    for (long long v = (long long)cb * 512 + tid; v < nvec; v += stride) {
      int b = (int)(v / pb);
      long long r = v - (long long)b * pb;
      float4 x = ((const float4*)ck)[v];
      half4v hx = { (_Float16)x.x, (_Float16)x.y, (_Float16)x.z, (_Float16)x.w };
      ((half4v*)Kc)[(long long)b * (TT * DM / 4) + r] = hx;
    }
  }
}

// ---------------- O-projection GEMM ----------------
__global__ __launch_bounds__(512, 4) void mm16o(
    const _Float16* __restrict__ Ain, const _Float16* __restrict__ W,
    const float* __restrict__ bias, float* __restrict__ Co)
{
  __shared__ __align__(16) char smem[4 * 8192];
  char* Abuf = smem;
  char* Wbuf = smem + 2 * 8192;

  const int tid = threadIdx.x;
  const int bm = blockIdx.x, bn = blockIdx.y;
  const int wid = tid >> 6, lane = tid & 63;
  const int wm = wid >> 2, wn = wid & 3;
  const int lr = lane & 15, lg = lane >> 4;

  f32x4 acc[4][2];
#pragma unroll
  for (int i = 0; i < 4; ++i)
#pragma unroll
    for (int j = 0; j < 2; ++j) acc[i][j] = (f32x4){0.f, 0.f, 0.f, 0.f};

  size_t aoff, woff;
  {
    const int o = wid * 1024 + lane * 16;
    const int prow = o >> 7, pb = o & 127;
    const int lb = pb ^ ((prow & 7) << 4);
    const int r = (prow << 1) | (lb >> 6), c = lb & 63;
    aoff = (size_t)(bm * 128 + r) * 4096 + c;
    woff = (size_t)(bn * 128 + r) * 4096 + c;
  }

  auto stage = [&](int kt, int buf) {
    gl_lds16((const char*)Ain + aoff + kt * 64, Abuf + buf * 8192 + wid * 1024 + (tid & 63) * 16);
    gl_lds16((const char*)W + woff + kt * 64, Wbuf + buf * 8192 + wid * 1024 + (tid & 63) * 16);
  };
  auto lds_addr = [](const char* base, int r, int cb) -> const char* {
    return base + ((r >> 1) << 7) + ((((r & 1) << 6) | cb) ^ (((r >> 1) & 7) << 4));
  };
  auto compute = [&](int buf) {
    const char* ab = Abuf + buf * 8192;
    const char* wb = Wbuf + buf * 8192;
    half8 af[4], bf[2];
#pragma unroll
    for (int i = 0; i < 4; ++i)
      af[i] = *(const half8*)lds_addr(ab, wm * 64 + i * 16 + lr, lg << 4);
#pragma unroll
    for (int j = 0; j < 2; ++j)
      bf[j] = *(const half8*)lds_addr(wb, wn * 32 + j * 16 + lr, lg << 4);
#pragma unroll
    for (int i = 0; i < 4; ++i)
#pragma unroll
      for (int j = 0; j < 2; ++j)
        acc[i][j] = __builtin_amdgcn_mfma_f32_16x16x32_f16(af[i], bf[j], acc[i][j], 0, 0, 0);
  };

  const int NKT = DM / 32;
  stage(0, 0);
  __syncthreads();
  for (int kt = 0; kt < NKT; ++kt) {
    if (kt + 1 < NKT) stage(kt + 1, (kt + 1) & 1);
    compute(kt & 1);
    __syncthreads();
  }

#pragma unroll
  for (int i = 0; i < 4; ++i) {
    const int m0 = bm * 128 + wm * 64 + i * 16 + lg * 4;
#pragma unroll
    for (int j = 0; j < 2; ++j) {
      const int gn = bn * 128 + wn * 32 + j * 16 + lr;
      const float bb = bias[gn];
#pragma unroll
      for (int r = 0; r < 4; ++r)
        Co[(size_t)(m0 + r) * DM + gn] = acc[i][j][r] + bb;
    }
  }
}

// ---------------- flash attention (R12-proven: kv-split x2, pipelined) ----------------
__global__ __launch_bounds__(512) void attn_kernel(
    const _Float16* __restrict__ Qp, const _Float16* __restrict__ Kc,
    const _Float16* __restrict__ Vt, _Float16* __restrict__ O0,
    _Float16* __restrict__ O1, float2* __restrict__ ml)
{
  __shared__ _Float16 Ks[2][64 * 128];
  __shared__ _Float16 VTs[3][128 * 64];
  __shared__ _Float16 Ps[8][32 * 64];

  const int tid = threadIdx.x;
  const int lin = blockIdx.x;
  const int xcd = lin & 7, slot = lin >> 3;
  const int pair = xcd * 8 + (slot >> 2);
  const int rem = slot & 3;
  const int qb = rem >> 1, part = rem & 1;
  const int b = pair >> 4, h = pair & 15;

  const int wid = tid >> 6, lane = tid & 63;
  const int lr = lane & 15, lg = lane >> 4;
  const int qw = qb * 256 + wid * 32;

  half8 qf[2][4];
#pragma unroll
  for (int qs = 0; qs < 2; ++qs)
#pragma unroll
    for (int kk = 0; kk < 4; ++kk)
      qf[qs][kk] = *(const half8*)&Qp[(size_t)(b * SQ + qw + qs * 16 + lr) * DM +
                                      h * DH + kk * 32 + lg * 8];

  f32x4 zero = {0.f, 0.f, 0.f, 0.f};
  f32x4 acc[8][2];
#pragma unroll
  for (int d = 0; d < 8; ++d)
#pragma unroll
    for (int qs = 0; qs < 2; ++qs) acc[d][qs] = zero;
  float m_run[2] = {-1e30f, -1e30f}, l_run[2] = {0.f, 0.f};

  const int nt_full = (CL + qb * 256 + 256) / 64;
  const int halfn = nt_full >> 1;
  const int tbeg = part ? halfn : 0;
  const int nt = part ? (nt_full - halfn) : halfn;

  int ksrc[2], vsrc[2];
#pragma unroll
  for (int c = 0; c < 2; ++c) {
    const int p = c * 512 + wid * 64 + lane;
    { const int r = p >> 4, pg = p & 15, gc = pg ^ (r & 7);
      ksrc[c] = r * DM + gc * 8; }
    { const int d = p >> 3, pg = p & 7, gt = pg ^ (d & 7);
      vsrc[c] = d * TT + gt * 8; }
  }
  const _Float16* Kb = Kc + (size_t)b * TT * DM + h * DH;
  const _Float16* Vb = Vt + (size_t)(b * NH + h) * DH * TT;

  auto stage = [&](int tt, int kbuf, int vbuf) {
    const int t0 = (tbeg + tt) * 64;
#pragma unroll
    for (int c = 0; c < 2; ++c)
      gl_lds16(Kb + (size_t)t0 * DM + ksrc[c], &Ks[kbuf][(c * 512 + wid * 64) * 8]);
#pragma unroll
    for (int c = 0; c < 2; ++c)
      gl_lds16(Vb + t0 + vsrc[c], &VTs[vbuf][(c * 512 + wid * 64) * 8]);
  };

  auto qk = [&](int kbuf, f32x4 (*s)[2]) {
#pragma unroll
    for (int j = 0; j < 4; ++j)
#pragma unroll
      for (int qs = 0; qs < 2; ++qs) s[j][qs] = zero;
#pragma unroll
    for (int kk = 0; kk < 4; ++kk)
#pragma unroll
      for (int j = 0; j < 4; ++j) {
        half8 kb = *(const half8*)&Ks[kbuf][KSW(j * 16 + lr, kk * 32 + lg * 8)];
        s[j][0] = __builtin_amdgcn_mfma_f32_16x16x32_f16(kb, qf[0][kk], s[j][0], 0, 0, 0);
        s[j][1] = __builtin_amdgcn_mfma_f32_16x16x32_f16(kb, qf[1][kk], s[j][1], 0, 0, 0);
      }
  };

  auto mask_s = [&](int t0, f32x4 (*s)[2]) {
    if (part && t0 + 63 > CL + qw) {
#pragma unroll
      for (int j = 0; j < 4; ++j)
#pragma unroll
        for (int qs = 0; qs < 2; ++qs)
#pragma unroll
          for (int r = 0; r < 4; ++r)
            if (t0 + j * 16 + lg * 4 + r > CL + qw + qs * 16 + lr) s[j][qs][r] = -1e30f;
    }
  };

  auto softmax_step = [&](f32x4 (*s)[2]) {
    float mt[2];
#pragma unroll
    for (int qs = 0; qs < 2; ++qs) {
      float m = s[0][qs][0];
#pragma unroll
      for (int j = 0; j < 4; ++j)
#pragma unroll
        for (int r = 0; r < 4; ++r) m = fmaxf(m, s[j][qs][r]);
      mt[qs] = m;
    }
    if (!__all(mt[0] <= m_run[0] + 10.0f && mt[1] <= m_run[1] + 10.0f)) {
#pragma unroll
      for (int qs = 0; qs < 2; ++qs) {
        float m = fmaxf(mt[qs], __shfl_xor(mt[qs], 16));
        m = fmaxf(m, __shfl_xor(m, 32));
        const float mn = fmaxf(m_run[qs], m);
        const float fsc = exp2f(m_run[qs] - mn);
        m_run[qs] = mn;
        l_run[qs] *= fsc;
#pragma unroll
        for (int d = 0; d < 8; ++d)
#pragma unroll
          for (int r = 0; r < 4; ++r) acc[d][qs][r] *= fsc;
      }
    }
#pragma unroll
    for (int qs = 0; qs < 2; ++qs) {
      float ps = 0.f;
#pragma unroll
      for (int j = 0; j < 4; ++j) {
        float p0 = exp2f(s[j][qs][0] - m_run[qs]);
        float p1 = exp2f(s[j][qs][1] - m_run[qs]);
        float p2 = exp2f(s[j][qs][2] - m_run[qs]);
        float p3 = exp2f(s[j][qs][3] - m_run[qs]);
        ps += (p0 + p1) + (p2 + p3);
        half4v hp = { (_Float16)p0, (_Float16)p1, (_Float16)p2, (_Float16)p3 };
        *(half4v*)&Ps[wid][PSW(qs * 16 + lr, j * 16 + lg * 4)] = hp;
      }
      l_run[qs] += ps;
    }
  };

  auto pv = [&](int vbuf) {
#pragma unroll
    for (int kk = 0; kk < 2; ++kk) {
      half8 pf0 = *(const half8*)&Ps[wid][PSW(lr, kk * 32 + lg * 8)];
      half8 pf1 = *(const half8*)&Ps[wid][PSW(16 + lr, kk * 32 + lg * 8)];
#pragma unroll
      for (int d = 0; d < 8; ++d) {
        half8 vf = *(const half8*)&VTs[vbuf][VSW(d * 16 + lr, kk * 32 + lg * 8)];
        acc[d][0] = __builtin_amdgcn_mfma_f32_16x16x32_f16(vf, pf0, acc[d][0], 0, 0, 0);
        acc[d][1] = __builtin_amdgcn_mfma_f32_16x16x32_f16(vf, pf1, acc[d][1], 0, 0, 0);
      }
    }
  };

  f32x4 sp[4][2], sc[4][2];

  stage(0, 0, 0);
  __syncthreads();
  stage(1, 1, 1);
  qk(0, sp);
  mask_s(tbeg * 64, sp);

  for (int t = 1; t < nt; ++t) {
    __syncthreads();
    if (t + 1 < nt) stage(t + 1, (t + 1) & 1, (t + 1) % 3);
    qk(t & 1, sc);
    softmax_step(sp);
    pv((t - 1) % 3);
    mask_s((tbeg + t) * 64, sc);
#pragma unroll
    for (int j = 0; j < 4; ++j)
#pragma unroll
      for (int qs = 0; qs < 2; ++qs) sp[j][qs] = sc[j][qs];
  }
  softmax_step(sp);
  pv((nt - 1) % 3);

  _Float16* Od = part ? O1 : O0;
#pragma unroll
  for (int qs = 0; qs < 2; ++qs) {
    float lt = l_run[qs] + __shfl_xor(l_run[qs], 16);
    lt += __shfl_xor(lt, 32);
    const float inv = 1.0f / lt;
#pragma unroll
    for (int d = 0; d < 8; ++d) {
      half4v hv;
#pragma unroll
      for (int r = 0; r < 4; ++r) hv[r] = (_Float16)(acc[d][qs][r] * inv);
      *(half4v*)&Od[(size_t)(b * SQ + qw + qs * 16 + lr) * DM + h * DH + d * 16 + lg * 4] = hv;
    }
    if (lg == 0) {
      float2 e; e.x = m_run[qs]; e.y = lt;
      ml[part * (64 * SQ) + ((b * NH + h) * SQ) + qw + qs * 16 + lr] = e;
    }
  }
}

// ---------------- combine the two kv-partitions ----------------
__global__ __launch_bounds__(256) void combine(
    _Float16* __restrict__ AO, const _Float16* __restrict__ O1,
    const float2* __restrict__ ml)
{
  const int idx = blockIdx.x * 256 + threadIdx.x;
  const int row = idx >> 8;
  const int col0 = (idx & 255) * 8;
  const int b = row >> 9, q = row & 511, h = col0 >> 7;
  const float2 e0 = ml[(b * NH + h) * SQ + q];
  const float2 e1 = ml[64 * SQ + (b * NH + h) * SQ + q];
  const float m = fmaxf(e0.x, e1.x);
  float w0 = e0.y * exp2f(e0.x - m);
  float w1 = e1.y * exp2f(e1.x - m);
  const float inv = 1.0f / (w0 + w1);
  w0 *= inv; w1 *= inv;
  const size_t o = (size_t)row * DM + col0;
  half8 a = *(const half8*)&AO[o];
  half8 c = *(const half8*)&O1[o];
  half8 r;
#pragma unroll
  for (int i = 0; i < 8; ++i)
    r[i] = (_Float16)(w0 * (float)a[i] + w1 * (float)c[i]);
  *(half8*)&AO[o] = r;
}

extern "C" void kernel_launch(void* const* d_in, const int* in_sizes, int n_in,
                              void* d_out, int out_size, void* d_ws, size_t ws_size,
                              hipStream_t stream) {
  const float* query = (const float*)d_in[0];
  const float* key   = (const float*)d_in[1];
  const float* value = (const float*)d_in[2];
  const float* ck    = (const float*)d_in[3];
  const float* cv    = (const float*)d_in[4];
  const float* wq = (const float*)d_in[5];
  const float* bq = (const float*)d_in[6];
  const float* wk = (const float*)d_in[7];
  const float* bk = (const float*)d_in[8];
  const float* wv = (const float*)d_in[9];
  const float* bv = (const float*)d_in[10];
  const float* wo = (const float*)d_in[11];
  const float* bo = (const float*)d_in[12];

  char* ws = (char*)d_ws;
  _Float16* Kc = (_Float16*)ws;                 // 64 MiB: [4][4096][2048]
  _Float16* Vt = (_Float16*)(ws + 67108864);    // 64 MiB: [4][16][128][4096]
  _Float16* Qp = (_Float16*)(ws + 134217728);   // 8 MiB
  _Float16* AO = (_Float16*)(ws + 142606336);   // 8 MiB

  // f16 input staging in dead regions: qh in AO (attn writes it later),
  // kh/vh in d_out (attn's O1s/mls rewrite it later). Weights read as fp32.
  _Float16* qh = AO;
  _Float16* kh = (_Float16*)d_out;
  _Float16* vh = (_Float16*)((char*)d_out + 8388608);
  _Float16* woh = Qp;

  _Float16* O1s = (_Float16*)d_out;                // 8 MiB
  float2* mls = (float2*)((char*)d_out + 8388608); // 512 KiB

  cvt_f16<<<dim3(512, 3), 256, 0, stream>>>(query, key, value, qh, kh, vh);
  fused_pre<<<768 + 3584 + 1024, 512, 0, stream>>>(
      qh, kh, vh, wq, wk, wv, bq, bk, bv, Qp, Kc, Vt, cv, ck);
  attn_kernel<<<256, 512, 0, stream>>>(Qp, Kc, Vt, AO, O1s, mls);
  combine<<<2048, 256, 0, stream>>>(AO, O1s, mls);
  cvt_f16_one<<<512, 256, 0, stream>>>(wo, woh);
  mm16o<<<dim3(16, 16), 512, 0, stream>>>(AO, woh, bo, (float*)d_out);
}

// Round 15
// 321.495 us; speedup vs baseline: 1.0540x; 1.0341x over previous
//
#include <hip/hip_runtime.h>

typedef _Float16 half8 __attribute__((ext_vector_type(8)));
typedef _Float16 half4v __attribute__((ext_vector_type(4)));
typedef float f32x4 __attribute__((ext_vector_type(4)));

#define NB 4
#define SQ 512
#define CL 3584
#define TT 4096
#define DM 2048
#define NH 16
#define DH 128

// XOR swizzles on half-index (attn LDS)
#define KSW(row, col) ((((row) * 128) + (col)) ^ ((((row) & 7) << 3)))
#define VSW(row, col) ((((row) * 64) + (col)) ^ ((((row) & 7) << 3)))
#define PSW(row, col) ((((row) * 64) + (col)) ^ ((((row) & 7) << 3)))

__device__ __forceinline__ void gl_lds16(const void* g, void* l) {
  __builtin_amdgcn_global_load_lds(
      (const __attribute__((address_space(1))) unsigned int*)g,
      (__attribute__((address_space(3))) unsigned int*)l, 16, 0, 0);
}

// ---------------- fp32 -> f16 dense convert, up to 7 slices in one launch ----------------
// z 0..2: q/k/v inputs; z 3..5: wq/wk/wv; z 6 (big-ws path only): wo
__global__ __launch_bounds__(256) void cvt_f16(
    const float* __restrict__ s0, const float* __restrict__ s1, const float* __restrict__ s2,
    const float* __restrict__ s3, const float* __restrict__ s4, const float* __restrict__ s5,
    const float* __restrict__ s6,
    _Float16* __restrict__ d0, _Float16* __restrict__ d1, _Float16* __restrict__ d2,
    _Float16* __restrict__ d3, _Float16* __restrict__ d4, _Float16* __restrict__ d5,
    _Float16* __restrict__ d6)
{
  const int z = blockIdx.y;
  const float* s = z == 0 ? s0 : z == 1 ? s1 : z == 2 ? s2 : z == 3 ? s3
                   : z == 4 ? s4 : z == 5 ? s5 : s6;
  _Float16* d = z == 0 ? d0 : z == 1 ? d1 : z == 2 ? d2 : z == 3 ? d3
                : z == 4 ? d4 : z == 5 ? d5 : d6;
  const int n4 = DM * DM / 4;
  for (int v = blockIdx.x * blockDim.x + threadIdx.x; v < n4;
       v += gridDim.x * blockDim.x) {
    float4 x = ((const float4*)s)[v];
    half4v h = { (_Float16)x.x, (_Float16)x.y, (_Float16)x.z, (_Float16)x.w };
    ((half4v*)d)[v] = h;
  }
}

// single-matrix variant for wo (fallback path: runs after attn; Qp region free)
__global__ __launch_bounds__(256) void cvt_f16_one(
    const float* __restrict__ s, _Float16* __restrict__ d)
{
  const int n4 = DM * DM / 4;
  for (int v = blockIdx.x * blockDim.x + threadIdx.x; v < n4;
       v += gridDim.x * blockDim.x) {
    float4 x = ((const float4*)s)[v];
    half4v h = { (_Float16)x.x, (_Float16)x.y, (_Float16)x.z, (_Float16)x.w };
    ((half4v*)d)[v] = h;
  }
}

// ---------------- cached K fp32 -> f16 linear convert ----------------
__global__ __launch_bounds__(256) void convert_K(
    const float* __restrict__ ck, _Float16* __restrict__ K)
{
  const long long nvec = (long long)NB * CL * DM / 4;
  const int pb = CL * DM / 4;
  for (long long v = (long long)blockIdx.x * blockDim.x + threadIdx.x; v < nvec;
       v += (long long)gridDim.x * blockDim.x) {
    int b = (int)(v / pb);
    long long r = v - (long long)b * pb;
    float4 x = ((const float4*)ck)[v];
    half4v hx = { (_Float16)x.x, (_Float16)x.y, (_Float16)x.z, (_Float16)x.w };
    ((half4v*)K)[(long long)b * (TT * DM / 4) + r] = hx;
  }
}

// ---------------- FUSED: QKV GEMM (bid<768) + cached-V transpose (bid>=768) ----------------
__global__ __launch_bounds__(512) void fused_pre(
    const _Float16* __restrict__ A0, const _Float16* __restrict__ A1,
    const _Float16* __restrict__ A2,
    const _Float16* __restrict__ W0, const _Float16* __restrict__ W1,
    const _Float16* __restrict__ W2,
    const float* __restrict__ b0, const float* __restrict__ b1,
    const float* __restrict__ b2,
    _Float16* __restrict__ Qp, _Float16* __restrict__ Kc,
    _Float16* __restrict__ Vt, const float* __restrict__ cv)
{
  __shared__ __align__(16) char smem[4 * 8192];

  const int bid = blockIdx.x;
  const int tid = threadIdx.x;

  if (bid < 768) {
    char* Abuf = smem;
    char* Wbuf = smem + 2 * 8192;
    const int bm = bid & 15, bn = (bid >> 4) & 15, z = bid >> 8;
    const _Float16* Ain = z == 0 ? A0 : z == 1 ? A1 : A2;
    const _Float16* W   = z == 0 ? W0 : z == 1 ? W1 : W2;
    const float* bias   = z == 0 ? b0 : z == 1 ? b1 : b2;

    const int wid = tid >> 6, lane = tid & 63;
    const int wm = wid >> 2, wn = wid & 3;
    const int lr = lane & 15, lg = lane >> 4;

    f32x4 acc[4][2];
#pragma unroll
    for (int i = 0; i < 4; ++i)
#pragma unroll
      for (int j = 0; j < 2; ++j) acc[i][j] = (f32x4){0.f, 0.f, 0.f, 0.f};

    size_t aoff, woff;
    {
      const int o = wid * 1024 + lane * 16;
      const int prow = o >> 7, pb = o & 127;
      const int lb = pb ^ ((prow & 7) << 4);
      const int r = (prow << 1) | (lb >> 6), c = lb & 63;
      aoff = (size_t)(bm * 128 + r) * 4096 + c;
      woff = (size_t)(bn * 128 + r) * 4096 + c;
    }

    auto stage = [&](int kt, int buf) {
      gl_lds16((const char*)Ain + aoff + kt * 64, Abuf + buf * 8192 + wid * 1024);
      gl_lds16((const char*)W + woff + kt * 64, Wbuf + buf * 8192 + wid * 1024);
    };
    auto lds_addr = [](const char* base, int r, int cb) -> const char* {
      return base + ((r >> 1) << 7) + ((((r & 1) << 6) | cb) ^ (((r >> 1) & 7) << 4));
    };
    auto compute = [&](int buf) {
      const char* ab = Abuf + buf * 8192;
      const char* wb = Wbuf + buf * 8192;
      half8 af[4], bf[2];
#pragma unroll
      for (int i = 0; i < 4; ++i)
        af[i] = *(const half8*)lds_addr(ab, wm * 64 + i * 16 + lr, lg << 4);
#pragma unroll
      for (int j = 0; j < 2; ++j)
        bf[j] = *(const half8*)lds_addr(wb, wn * 32 + j * 16 + lr, lg << 4);
#pragma unroll
      for (int i = 0; i < 4; ++i)
#pragma unroll
        for (int j = 0; j < 2; ++j)
          acc[i][j] = __builtin_amdgcn_mfma_f32_16x16x32_f16(af[i], bf[j], acc[i][j], 0, 0, 0);
    };

    const int NKT = DM / 32;
    stage(0, 0);
    __syncthreads();
    for (int kt = 0; kt < NKT; ++kt) {
      if (kt + 1 < NKT) stage(kt + 1, (kt + 1) & 1);
      compute(kt & 1);
      __syncthreads();
    }

    const float qscale = 0.08838834764831845f * 1.4426950408889634f;
#pragma unroll
    for (int i = 0; i < 4; ++i) {
      const int m0 = bm * 128 + wm * 64 + i * 16 + lg * 4;
#pragma unroll
      for (int j = 0; j < 2; ++j) {
        const int gn = bn * 128 + wn * 32 + j * 16 + lr;
        const float bb = bias[gn];
        if (z == 0) {
#pragma unroll
          for (int r = 0; r < 4; ++r)
            Qp[(size_t)(m0 + r) * DM + gn] = (_Float16)((acc[i][j][r] + bb) * qscale);
        } else if (z == 1) {
          const int b = m0 >> 9;
#pragma unroll
          for (int r = 0; r < 4; ++r)
            Kc[((size_t)b * TT + CL + ((m0 + r) & 511)) * DM + gn] =
                (_Float16)(acc[i][j][r] + bb);
        } else {
          half4v hv;
#pragma unroll
          for (int r = 0; r < 4; ++r) hv[r] = (_Float16)(acc[i][j][r] + bb);
          const int b = m0 >> 9, t = CL + (m0 & 511);
          const int h = gn >> 7, d = gn & 127;
          *(half4v*)&Vt[((size_t)(b * NH + h) * DH + d) * TT + t] = hv;
        }
      }
    }
  } else {
    _Float16 (*T)[136] = (_Float16(*)[136])smem;
    const int tv = bid - 768;
    const int b = tv / 896;
    const int rem = tv - b * 896;
    const int t0 = (rem % 56) * 64;
    const int dm0 = (rem / 56) * 128;
    {
      const int tr = tid >> 3, c0 = (tid & 7) * 16;
      const float* src = cv + ((size_t)b * CL + t0 + tr) * DM + dm0 + c0;
      float4 a0 = ((const float4*)src)[0];
      float4 a1 = ((const float4*)src)[1];
      float4 a2 = ((const float4*)src)[2];
      float4 a3 = ((const float4*)src)[3];
      half8 h0 = { (_Float16)a0.x, (_Float16)a0.y, (_Float16)a0.z, (_Float16)a0.w,
                   (_Float16)a1.x, (_Float16)a1.y, (_Float16)a1.z, (_Float16)a1.w };
      half8 h1 = { (_Float16)a2.x, (_Float16)a2.y, (_Float16)a2.z, (_Float16)a2.w,
                   (_Float16)a3.x, (_Float16)a3.y, (_Float16)a3.z, (_Float16)a3.w };
      *(half8*)&T[tr][c0] = h0;
      *(half8*)&T[tr][c0 + 8] = h1;
    }
    __syncthreads();
    {
      const int dl = tid >> 2, tc = (tid & 3) * 16;
      const int h = dm0 >> 7;
      half8 o0, o1;
#pragma unroll
      for (int i = 0; i < 8; ++i) o0[i] = T[tc + i][dl];
#pragma unroll
      for (int i = 0; i < 8; ++i) o1[i] = T[tc + 8 + i][dl];
      _Float16* dst = Vt + ((size_t)(b * NH + h) * DH + dl) * TT + t0 + tc;
      *(half8*)dst = o0;
      *(half8*)(dst + 8) = o1;
    }
  }
}

// ---------------- O-projection GEMM (f16 A via gl_lds, fp32 out) ----------------
__global__ __launch_bounds__(512, 4) void mm16o(
    const _Float16* __restrict__ Ain, const _Float16* __restrict__ W,
    const float* __restrict__ bias, float* __restrict__ Co)
{
  __shared__ __align__(16) char smem[4 * 8192];
  char* Abuf = smem;
  char* Wbuf = smem + 2 * 8192;

  const int tid = threadIdx.x;
  const int bm = blockIdx.x, bn = blockIdx.y;
  const int wid = tid >> 6, lane = tid & 63;
  const int wm = wid >> 2, wn = wid & 3;
  const int lr = lane & 15, lg = lane >> 4;

  f32x4 acc[4][2];
#pragma unroll
  for (int i = 0; i < 4; ++i)
#pragma unroll
    for (int j = 0; j < 2; ++j) acc[i][j] = (f32x4){0.f, 0.f, 0.f, 0.f};

  size_t aoff, woff;
  {
    const int o = wid * 1024 + lane * 16;
    const int prow = o >> 7, pb = o & 127;
    const int lb = pb ^ ((prow & 7) << 4);
    const int r = (prow << 1) | (lb >> 6), c = lb & 63;
    aoff = (size_t)(bm * 128 + r) * 4096 + c;
    woff = (size_t)(bn * 128 + r) * 4096 + c;
  }

  auto stage = [&](int kt, int buf) {
    gl_lds16((const char*)Ain + aoff + kt * 64, Abuf + buf * 8192 + wid * 1024);
    gl_lds16((const char*)W + woff + kt * 64, Wbuf + buf * 8192 + wid * 1024);
  };
  auto lds_addr = [](const char* base, int r, int cb) -> const char* {
    return base + ((r >> 1) << 7) + ((((r & 1) << 6) | cb) ^ (((r >> 1) & 7) << 4));
  };
  auto compute = [&](int buf) {
    const char* ab = Abuf + buf * 8192;
    const char* wb = Wbuf + buf * 8192;
    half8 af[4], bf[2];
#pragma unroll
    for (int i = 0; i < 4; ++i)
      af[i] = *(const half8*)lds_addr(ab, wm * 64 + i * 16 + lr, lg << 4);
#pragma unroll
    for (int j = 0; j < 2; ++j)
      bf[j] = *(const half8*)lds_addr(wb, wn * 32 + j * 16 + lr, lg << 4);
#pragma unroll
    for (int i = 0; i < 4; ++i)
#pragma unroll
      for (int j = 0; j < 2; ++j)
        acc[i][j] = __builtin_amdgcn_mfma_f32_16x16x32_f16(af[i], bf[j], acc[i][j], 0, 0, 0);
  };

  const int NKT = DM / 32;
  stage(0, 0);
  __syncthreads();
  for (int kt = 0; kt < NKT; ++kt) {
    if (kt + 1 < NKT) stage(kt + 1, (kt + 1) & 1);
    compute(kt & 1);
    __syncthreads();
  }

#pragma unroll
  for (int i = 0; i < 4; ++i) {
    const int m0 = bm * 128 + wm * 64 + i * 16 + lg * 4;
#pragma unroll
    for (int j = 0; j < 2; ++j) {
      const int gn = bn * 128 + wn * 32 + j * 16 + lr;
      const float bb = bias[gn];
#pragma unroll
      for (int r = 0; r < 4; ++r)
        Co[(size_t)(m0 + r) * DM + gn] = acc[i][j][r] + bb;
    }
  }
}

// ---------------- flash attention (R12-proven: kv-split x2, pipelined) ----------------
__global__ __launch_bounds__(512) void attn_kernel(
    const _Float16* __restrict__ Qp, const _Float16* __restrict__ Kc,
    const _Float16* __restrict__ Vt, _Float16* __restrict__ O0,
    _Float16* __restrict__ O1, float2* __restrict__ ml)
{
  __shared__ _Float16 Ks[2][64 * 128];
  __shared__ _Float16 VTs[3][128 * 64];
  __shared__ _Float16 Ps[8][32 * 64];

  const int tid = threadIdx.x;
  const int lin = blockIdx.x;
  const int xcd = lin & 7, slot = lin >> 3;
  const int pair = xcd * 8 + (slot >> 2);
  const int rem = slot & 3;
  const int qb = rem >> 1, part = rem & 1;
  const int b = pair >> 4, h = pair & 15;

  const int wid = tid >> 6, lane = tid & 63;
  const int lr = lane & 15, lg = lane >> 4;
  const int qw = qb * 256 + wid * 32;

  half8 qf[2][4];
#pragma unroll
  for (int qs = 0; qs < 2; ++qs)
#pragma unroll
    for (int kk = 0; kk < 4; ++kk)
      qf[qs][kk] = *(const half8*)&Qp[(size_t)(b * SQ + qw + qs * 16 + lr) * DM +
                                      h * DH + kk * 32 + lg * 8];

  f32x4 zero = {0.f, 0.f, 0.f, 0.f};
  f32x4 acc[8][2];
#pragma unroll
  for (int d = 0; d < 8; ++d)
#pragma unroll
    for (int qs = 0; qs < 2; ++qs) acc[d][qs] = zero;
  float m_run[2] = {-1e30f, -1e30f}, l_run[2] = {0.f, 0.f};

  const int nt_full = (CL + qb * 256 + 256) / 64;
  const int halfn = nt_full >> 1;
  const int tbeg = part ? halfn : 0;
  const int nt = part ? (nt_full - halfn) : halfn;

  int ksrc[2], vsrc[2];
#pragma unroll
  for (int c = 0; c < 2; ++c) {
    const int p = c * 512 + wid * 64 + lane;
    { const int r = p >> 4, pg = p & 15, gc = pg ^ (r & 7);
      ksrc[c] = r * DM + gc * 8; }
    { const int d = p >> 3, pg = p & 7, gt = pg ^ (d & 7);
      vsrc[c] = d * TT + gt * 8; }
  }
  const _Float16* Kb = Kc + (size_t)b * TT * DM + h * DH;
  const _Float16* Vb = Vt + (size_t)(b * NH + h) * DH * TT;

  auto stage = [&](int tt, int kbuf, int vbuf) {
    const int t0 = (tbeg + tt) * 64;
#pragma unroll
    for (int c = 0; c < 2; ++c)
      gl_lds16(Kb + (size_t)t0 * DM + ksrc[c], &Ks[kbuf][(c * 512 + wid * 64) * 8]);
#pragma unroll
    for (int c = 0; c < 2; ++c)
      gl_lds16(Vb + t0 + vsrc[c], &VTs[vbuf][(c * 512 + wid * 64) * 8]);
  };

  auto qk = [&](int kbuf, f32x4 (*s)[2]) {
#pragma unroll
    for (int j = 0; j < 4; ++j)
#pragma unroll
      for (int qs = 0; qs < 2; ++qs) s[j][qs] = zero;
#pragma unroll
    for (int kk = 0; kk < 4; ++kk)
#pragma unroll
      for (int j = 0; j < 4; ++j) {
        half8 kb = *(const half8*)&Ks[kbuf][KSW(j * 16 + lr, kk * 32 + lg * 8)];
        s[j][0] = __builtin_amdgcn_mfma_f32_16x16x32_f16(kb, qf[0][kk], s[j][0], 0, 0, 0);
        s[j][1] = __builtin_amdgcn_mfma_f32_16x16x32_f16(kb, qf[1][kk], s[j][1], 0, 0, 0);
      }
  };

  auto mask_s = [&](int t0, f32x4 (*s)[2]) {
    if (part && t0 + 63 > CL + qw) {
#pragma unroll
      for (int j = 0; j < 4; ++j)
#pragma unroll
        for (int qs = 0; qs < 2; ++qs)
#pragma unroll
          for (int r = 0; r < 4; ++r)
            if (t0 + j * 16 + lg * 4 + r > CL + qw + qs * 16 + lr) s[j][qs][r] = -1e30f;
    }
  };

  auto softmax_step = [&](f32x4 (*s)[2]) {
    float mt[2];
#pragma unroll
    for (int qs = 0; qs < 2; ++qs) {
      float m = s[0][qs][0];
#pragma unroll
      for (int j = 0; j < 4; ++j)
#pragma unroll
        for (int r = 0; r < 4; ++r) m = fmaxf(m, s[j][qs][r]);
      mt[qs] = m;
    }
    if (!__all(mt[0] <= m_run[0] + 10.0f && mt[1] <= m_run[1] + 10.0f)) {
#pragma unroll
      for (int qs = 0; qs < 2; ++qs) {
        float m = fmaxf(mt[qs], __shfl_xor(mt[qs], 16));
        m = fmaxf(m, __shfl_xor(m, 32));
        const float mn = fmaxf(m_run[qs], m);
        const float fsc = exp2f(m_run[qs] - mn);
        m_run[qs] = mn;
        l_run[qs] *= fsc;
#pragma unroll
        for (int d = 0; d < 8; ++d)
#pragma unroll
          for (int r = 0; r < 4; ++r) acc[d][qs][r] *= fsc;
      }
    }
#pragma unroll
    for (int qs = 0; qs < 2; ++qs) {
      float ps = 0.f;
#pragma unroll
      for (int j = 0; j < 4; ++j) {
        float p0 = exp2f(s[j][qs][0] - m_run[qs]);
        float p1 = exp2f(s[j][qs][1] - m_run[qs]);
        float p2 = exp2f(s[j][qs][2] - m_run[qs]);
        float p3 = exp2f(s[j][qs][3] - m_run[qs]);
        ps += (p0 + p1) + (p2 + p3);
        half4v hp = { (_Float16)p0, (_Float16)p1, (_Float16)p2, (_Float16)p3 };
        *(half4v*)&Ps[wid][PSW(qs * 16 + lr, j * 16 + lg * 4)] = hp;
      }
      l_run[qs] += ps;
    }
  };

  auto pv = [&](int vbuf) {
#pragma unroll
    for (int kk = 0; kk < 2; ++kk) {
      half8 pf0 = *(const half8*)&Ps[wid][PSW(lr, kk * 32 + lg * 8)];
      half8 pf1 = *(const half8*)&Ps[wid][PSW(16 + lr, kk * 32 + lg * 8)];
#pragma unroll
      for (int d = 0; d < 8; ++d) {
        half8 vf = *(const half8*)&VTs[vbuf][VSW(d * 16 + lr, kk * 32 + lg * 8)];
        acc[d][0] = __builtin_amdgcn_mfma_f32_16x16x32_f16(vf, pf0, acc[d][0], 0, 0, 0);
        acc[d][1] = __builtin_amdgcn_mfma_f32_16x16x32_f16(vf, pf1, acc[d][1], 0, 0, 0);
      }
    }
  };

  f32x4 sp[4][2], sc[4][2];

  stage(0, 0, 0);
  __syncthreads();
  stage(1, 1, 1);
  qk(0, sp);
  mask_s(tbeg * 64, sp);

  for (int t = 1; t < nt; ++t) {
    __syncthreads();
    if (t + 1 < nt) stage(t + 1, (t + 1) & 1, (t + 1) % 3);
    qk(t & 1, sc);
    softmax_step(sp);
    pv((t - 1) % 3);
    mask_s((tbeg + t) * 64, sc);
#pragma unroll
    for (int j = 0; j < 4; ++j)
#pragma unroll
      for (int qs = 0; qs < 2; ++qs) sp[j][qs] = sc[j][qs];
  }
  softmax_step(sp);
  pv((nt - 1) % 3);

  _Float16* Od = part ? O1 : O0;
#pragma unroll
  for (int qs = 0; qs < 2; ++qs) {
    float lt = l_run[qs] + __shfl_xor(l_run[qs], 16);
    lt += __shfl_xor(lt, 32);
    const float inv = 1.0f / lt;
#pragma unroll
    for (int d = 0; d < 8; ++d) {
      half4v hv;
#pragma unroll
      for (int r = 0; r < 4; ++r) hv[r] = (_Float16)(acc[d][qs][r] * inv);
      *(half4v*)&Od[(size_t)(b * SQ + qw + qs * 16 + lr) * DM + h * DH + d * 16 + lg * 4] = hv;
    }
    if (lg == 0) {
      float2 e; e.x = m_run[qs]; e.y = lt;
      ml[part * (64 * SQ) + ((b * NH + h) * SQ) + qw + qs * 16 + lr] = e;
    }
  }
}

// ---------------- combine the two kv-partitions ----------------
__global__ __launch_bounds__(256) void combine(
    _Float16* __restrict__ AO, const _Float16* __restrict__ O1,
    const float2* __restrict__ ml)
{
  const int idx = blockIdx.x * 256 + threadIdx.x;
  const int row = idx >> 8;
  const int col0 = (idx & 255) * 8;
  const int b = row >> 9, q = row & 511, h = col0 >> 7;
  const float2 e0 = ml[(b * NH + h) * SQ + q];
  const float2 e1 = ml[64 * SQ + (b * NH + h) * SQ + q];
  const float m = fmaxf(e0.x, e1.x);
  float w0 = e0.y * exp2f(e0.x - m);
  float w1 = e1.y * exp2f(e1.x - m);
  const float inv = 1.0f / (w0 + w1);
  w0 *= inv; w1 *= inv;
  const size_t o = (size_t)row * DM + col0;
  half8 a = *(const half8*)&AO[o];
  half8 c = *(const half8*)&O1[o];
  half8 r;
#pragma unroll
  for (int i = 0; i < 8; ++i)
    r[i] = (_Float16)(w0 * (float)a[i] + w1 * (float)c[i]);
  *(half8*)&AO[o] = r;
}

extern "C" void kernel_launch(void* const* d_in, const int* in_sizes, int n_in,
                              void* d_out, int out_size, void* d_ws, size_t ws_size,
                              hipStream_t stream) {
  const float* query = (const float*)d_in[0];
  const float* key   = (const float*)d_in[1];
  const float* value = (const float*)d_in[2];
  const float* ck    = (const float*)d_in[3];
  const float* cv    = (const float*)d_in[4];
  const float* wq = (const float*)d_in[5];
  const float* bq = (const float*)d_in[6];
  const float* wk = (const float*)d_in[7];
  const float* bk = (const float*)d_in[8];
  const float* wv = (const float*)d_in[9];
  const float* bv = (const float*)d_in[10];
  const float* wo = (const float*)d_in[11];
  const float* bo = (const float*)d_in[12];

  char* ws = (char*)d_ws;
  _Float16* Kc = (_Float16*)ws;                 // 64 MiB: [4][4096][2048]
  _Float16* Vt = (_Float16*)(ws + 67108864);    // 64 MiB: [4][16][128][4096]
  _Float16* Qp = (_Float16*)(ws + 134217728);   // 8 MiB
  _Float16* AO = (_Float16*)(ws + 142606336);   // 8 MiB (ends at 144 MiB)

  // staging in dead regions (R12-proven):
  // qh in AO (attn writes AO later); kh/vh in d_out (attn's O1s/mls rewrite later);
  // wq/wk/wv f16 in Kc cache stripes (t<3584) of b0/b1/b2 — disjoint from K-scatter
  // (t>=3584); convert_K overwrites them after fused_pre.
  _Float16* qh = AO;
  _Float16* kh = (_Float16*)d_out;
  _Float16* vh = (_Float16*)((char*)d_out + 8388608);
  _Float16* wqh = Kc;
  _Float16* wkh = (_Float16*)(ws + 16777216);
  _Float16* wvh = (_Float16*)(ws + 33554432);

  _Float16* O1s = (_Float16*)d_out;                // 8 MiB
  float2* mls = (float2*)((char*)d_out + 8388608); // 512 KiB

  // wo f16: early (7th cvt slice) into ws+144MiB if workspace allows (R13 verified
  // allocations to 153 MiB), else post-attn into Qp (R12 fallback).
  const bool big = ws_size >= (size_t)153 * 1024 * 1024;
  _Float16* woh = big ? (_Float16*)(ws + 150994944) : Qp;

  cvt_f16<<<dim3(512, big ? 7 : 6), 256, 0, stream>>>(
      query, key, value, wq, wk, wv, wo, qh, kh, vh, wqh, wkh, wvh, woh);
  fused_pre<<<768 + 3584, 512, 0, stream>>>(
      qh, kh, vh, wqh, wkh, wvh, bq, bk, bv, Qp, Kc, Vt, cv);
  convert_K<<<2048, 256, 0, stream>>>(ck, Kc);
  attn_kernel<<<256, 512, 0, stream>>>(Qp, Kc, Vt, AO, O1s, mls);
  combine<<<2048, 256, 0, stream>>>(AO, O1s, mls);
  if (!big) cvt_f16_one<<<512, 256, 0, stream>>>(wo, woh);
  mm16o<<<dim3(16, 16), 512, 0, stream>>>(AO, woh, bo, (float*)d_out);
}